// Round 21
// baseline (269.101 us; speedup 1.0000x reference)
//
#include <hip/hip_runtime.h>
#include <hip/hip_bf16.h>

#define H      2048
#define IN     1408
#define NE     8
#define NTOK   2048
#define NSLOT  (NTOK*2)
#define GUPR   (2*IN)
#define NCVT   4096

typedef __attribute__((ext_vector_type(8))) short bf16x8;
typedef __attribute__((ext_vector_type(4))) float f32x4;
typedef __attribute__((ext_vector_type(4))) unsigned int u32x4;

__device__ __forceinline__ ushort f2bf(float f) {
  unsigned u = __float_as_uint(f);
  return (ushort)((u + 0x7FFFu + ((u >> 16) & 1u)) >> 16);
}
__device__ __forceinline__ unsigned pack2(float lo, float hi) {
  return (unsigned)f2bf(lo) | ((unsigned)f2bf(hi) << 16);
}
__device__ __forceinline__ float bf2f(ushort u) {
  return __uint_as_float((unsigned)u << 16);
}

#define GLOAD_LDS16(gp, lp) __builtin_amdgcn_global_load_lds((const __attribute__((address_space(1))) void*)(gp), (__attribute__((address_space(3))) void*)(lp), 16, 0, 0)

// fused prep: blocks [0,NCVT) = grid-strided f32->bf16 weight convert
// (seg1 = gate_up row-interleaved: gate i -> 2i, up i -> 2i+1; seg2 = down);
// blocks [NCVT, NCVT+NTOK) = router (logits, top-2, xb).
// cvt: 64B nontemporal read / 2x16B write per thread per iteration.
// i indexes 32B-dest units (8 bf16 pairs -> 2 u32x4 stores).
__global__ __launch_bounds__(256) void prep_kernel(
    const float* __restrict__ x, const float* __restrict__ gw,
    float* __restrict__ logits_out,
    int* __restrict__ topk_idx, float* __restrict__ topk_w,
    ushort* __restrict__ xb,
    const f32x4* __restrict__ s1, u32x4* __restrict__ d1, int u1,
    const f32x4* __restrict__ s2, u32x4* __restrict__ d2, int u2) {
  __shared__ float xs[H];
  __shared__ float lg[NE];
  if (blockIdx.x < NCVT) {
    int total = u1 + u2;                    // 32B-dest units
    for (int i = blockIdx.x * 256 + threadIdx.x; i < total; i += NCVT * 256) {
      f32x4 a0, a1, a2, a3;
      u32x4* dp;
      if (i < u1) {
        const f32x4* s = s1 + 4 * (size_t)i;
        a0 = __builtin_nontemporal_load(s);
        a1 = __builtin_nontemporal_load(s + 1);
        a2 = __builtin_nontemporal_load(s + 2);
        a3 = __builtin_nontemporal_load(s + 3);
        int r = i >> 7, c = i & 127;        // 128 32B-units per H-row
        int re = r % GUPR;
        int pr = (re < IN) ? (re << 1) : (((re - IN) << 1) | 1);
        dp = d1 + 2 * ((size_t)(r - re + pr) * 128 + c);
      } else {
        int j = i - u1;
        const f32x4* s = s2 + 4 * (size_t)j;
        a0 = __builtin_nontemporal_load(s);
        a1 = __builtin_nontemporal_load(s + 1);
        a2 = __builtin_nontemporal_load(s + 2);
        a3 = __builtin_nontemporal_load(s + 3);
        dp = d2 + 2 * (size_t)j;
      }
      u32x4 o0, o1;
      o0.x = pack2(a0.x, a0.y); o0.y = pack2(a0.z, a0.w);
      o0.z = pack2(a1.x, a1.y); o0.w = pack2(a1.z, a1.w);
      o1.x = pack2(a2.x, a2.y); o1.y = pack2(a2.z, a2.w);
      o1.z = pack2(a3.x, a3.y); o1.w = pack2(a3.z, a3.w);
      dp[0] = o0; dp[1] = o1;
    }
    return;
  }
  // ---- router path ----
  int n = blockIdx.x - NCVT;
  const float* xr = x + (size_t)n * H;
  for (int i = threadIdx.x; i < H / 4; i += 256)
    ((float4*)xs)[i] = ((const float4*)xr)[i];
  __syncthreads();
  {
    int t = threadIdx.x;
    float4 v0 = ((const float4*)xs)[t * 2];
    float4 v1 = ((const float4*)xs)[t * 2 + 1];
    uint4 o;
    o.x = pack2(v0.x, v0.y); o.y = pack2(v0.z, v0.w);
    o.z = pack2(v1.x, v1.y); o.w = pack2(v1.z, v1.w);
    *(uint4*)(xb + (size_t)n * H + t * 8) = o;
  }
  int e = threadIdx.x >> 5;
  int l32 = threadIdx.x & 31;
  const float* w = gw + (size_t)e * H;
  float p = 0.f;
  for (int i = l32; i < H; i += 32) p += xs[i] * w[i];
#pragma unroll
  for (int o = 16; o; o >>= 1) p += __shfl_xor(p, o);
  if (l32 == 0) lg[e] = p;
  __syncthreads();
  if (threadIdx.x < NE) logits_out[(size_t)n * NE + threadIdx.x] = lg[threadIdx.x];
  if (threadIdx.x == 0) {
    int i1 = 0; float v1 = lg[0];
    for (int k = 1; k < NE; ++k) if (lg[k] > v1) { v1 = lg[k]; i1 = k; }
    int i2 = -1; float v2 = -1e30f;
    for (int k = 0; k < NE; ++k) if (k != i1 && lg[k] > v2) { v2 = lg[k]; i2 = k; }
    float ed = __expf(v2 - v1);
    topk_idx[n * 2 + 0] = i1; topk_idx[n * 2 + 1] = i2;
    topk_w[n * 2 + 0] = 1.f / (1.f + ed);
    topk_w[n * 2 + 1] = ed / (1.f + ed);
  }
}

// fused count + scan + scatter: ONE block, 1024 threads, LDS counters/cursors
__global__ __launch_bounds__(1024) void scatter_kernel(
    const int* __restrict__ topk_idx, const float* __restrict__ topk_w,
    int* __restrict__ counts, int* __restrict__ offsets,
    int* __restrict__ slot_token, float* __restrict__ slot_w,
    int* __restrict__ tok2slot) {
  __shared__ int cnt_s[NE];
  __shared__ int curs[NE];
  if (threadIdx.x < NE) cnt_s[threadIdx.x] = 0;
  __syncthreads();
  for (int n = threadIdx.x; n < NTOK; n += 1024) {
    atomicAdd(&cnt_s[topk_idx[n * 2 + 0]], 1);
    atomicAdd(&cnt_s[topk_idx[n * 2 + 1]], 1);
  }
  __syncthreads();
  if (threadIdx.x == 0) {
    int s = 0;
    for (int e = 0; e < NE; ++e) {
      counts[e] = cnt_s[e];
      offsets[e] = s; curs[e] = s; s += cnt_s[e];
    }
  }
  __syncthreads();
  for (int n = threadIdx.x; n < NTOK; n += 1024) {
    for (int k = 0; k < 2; ++k) {
      int e = topk_idx[n * 2 + k];
      int s = atomicAdd(&curs[e], 1);
      slot_token[s] = n;
      slot_w[s] = topk_w[n * 2 + k];
      tok2slot[n * 2 + k] = s;
    }
  }
}

// LDS tile [128 rows][64 bf16]; physical 16B-slot q holds logical slot q^(row&7)
__device__ __forceinline__ bf16x8 read_frag(const ushort* lds, int row, int kk, int lane) {
  int slot = (kk * 4 + (lane >> 4)) ^ (row & 7);
  return *(const bf16x8*)(lds + row * 64 + slot * 8);
}

// GEMM1: act = silu(x@Wg^T) * (x@Wu^T)  [R10-proven structure]
// block: 128 slots x 128 interleaved gup rows; BK=64; SINGLE buffer (32KB LDS)
// 4 waves 2Mx2N, wave tile 64x64; silu pairing via shfl_xor(1)
__global__ __launch_bounds__(256) void gemm1_kernel(
    const ushort* __restrict__ xb, const ushort* __restrict__ gupb,
    const int* __restrict__ offsets, const int* __restrict__ counts,
    const int* __restrict__ slot_token, ushort* __restrict__ act) {
  int e = blockIdx.z, mt = blockIdx.y, nt = blockIdx.x;
  int cnt = counts[e];
  if (mt * 128 >= cnt) return;
  int off = offsets[e];
  __shared__ ushort As[128 * 64], Bs[128 * 64];
  int tid = threadIdx.x, lane = tid & 63, wid = tid >> 6;
  int wm = (wid >> 1) * 64, wn = (wid & 1) * 64;
  int q = tid & 7;

  const ushort* aSrc[4];
#pragma unroll
  for (int it = 0; it < 4; ++it) {
    int row = (it * 256 + tid) >> 3;
    int grow = mt * 128 + row; if (grow >= cnt) grow = cnt - 1;
    int token = slot_token[off + grow];
    aSrc[it] = xb + (size_t)token * H + (size_t)((q ^ (row & 7)) * 8);
  }
  const ushort* bSrc[4];
#pragma unroll
  for (int it = 0; it < 4; ++it) {
    int row = (it * 256 + tid) >> 3;
    bSrc[it] = gupb + ((size_t)e * GUPR + nt * 128 + row) * H + (size_t)((q ^ (row & 7)) * 8);
  }

  f32x4 zz = {0.f, 0.f, 0.f, 0.f};
  f32x4 acc[4][4];
#pragma unroll
  for (int mi = 0; mi < 4; ++mi)
#pragma unroll
    for (int ni = 0; ni < 4; ++ni) acc[mi][ni] = zz;

  for (int k0 = 0; k0 < H; k0 += 64) {
#pragma unroll
    for (int it = 0; it < 4; ++it) {
      GLOAD_LDS16(aSrc[it] + k0, &As[it * 2048 + tid * 8]);
      GLOAD_LDS16(bSrc[it] + k0, &Bs[it * 2048 + tid * 8]);
    }
    __syncthreads();
#pragma unroll
    for (int kk = 0; kk < 2; ++kk) {
      bf16x8 af[4], bf[4];
#pragma unroll
      for (int mi = 0; mi < 4; ++mi)
        af[mi] = read_frag(As, wm + mi * 16 + (lane & 15), kk, lane);
#pragma unroll
      for (int ni = 0; ni < 4; ++ni)
        bf[ni] = read_frag(Bs, wn + ni * 16 + (lane & 15), kk, lane);
#pragma unroll
      for (int mi = 0; mi < 4; ++mi)
#pragma unroll
        for (int ni = 0; ni < 4; ++ni)
          acc[mi][ni] = __builtin_amdgcn_mfma_f32_16x16x32_bf16(af[mi], bf[ni], acc[mi][ni], 0, 0, 0);
    }
    __syncthreads();
  }

  // epilogue: permuted col p = wn + ni*16 + (lane&15); even p = gate, odd = up
  int rb = mt * 128 + wm + ((lane >> 4) << 2);
  int colh = (lane & 15) >> 1;
  bool evenlane = (lane & 1) == 0;
#pragma unroll
  for (int mi = 0; mi < 4; ++mi)
#pragma unroll
    for (int r = 0; r < 4; ++r) {
      int mrow = rb + mi * 16 + r;
      bool wr = evenlane && (mrow < cnt);
      size_t rowo = wr ? (size_t)(off + mrow) * IN : 0;
#pragma unroll
      for (int ni = 0; ni < 4; ++ni) {
        float v = acc[mi][ni][r];
        float o = __shfl_xor(v, 1);
        if (wr) {
          float g = v, u = o;
          float a2 = g / (1.f + __expf(-g)) * u;
          act[rowo + nt * 64 + (wn >> 1) + ni * 8 + colh] = f2bf(a2);
        }
      }
    }
}

// GEMM2: eo[slot] = w * (act @ Wd^T)  [R10-proven structure]
// block: 128 slots x 128 H-cols; BK=64; SINGLE buffer; 4 waves 2Mx2N
__global__ __launch_bounds__(256) void gemm2_kernel(
    const ushort* __restrict__ act, const ushort* __restrict__ downb,
    const int* __restrict__ offsets, const int* __restrict__ counts,
    const float* __restrict__ slot_w, ushort* __restrict__ eo) {
  int e = blockIdx.z, mt = blockIdx.y, nt = blockIdx.x;
  int cnt = counts[e];
  if (mt * 128 >= cnt) return;
  int off = offsets[e];
  __shared__ ushort As[128 * 64], Bs[128 * 64];
  int tid = threadIdx.x, lane = tid & 63, wid = tid >> 6;
  int wm = (wid >> 1) * 64, wn = (wid & 1) * 64;
  int q = tid & 7;

  const ushort* aSrc[4];
#pragma unroll
  for (int it = 0; it < 4; ++it) {
    int row = (it * 256 + tid) >> 3;
    int grow = mt * 128 + row; if (grow >= cnt) grow = cnt - 1;
    aSrc[it] = act + (size_t)(off + grow) * IN + (size_t)((q ^ (row & 7)) * 8);
  }
  const ushort* bSrc[4];
#pragma unroll
  for (int it = 0; it < 4; ++it) {
    int row = (it * 256 + tid) >> 3;
    bSrc[it] = downb + ((size_t)e * H + nt * 128 + row) * IN + (size_t)((q ^ (row & 7)) * 8);
  }

  f32x4 zz = {0.f, 0.f, 0.f, 0.f};
  f32x4 acc[4][4];
#pragma unroll
  for (int mi = 0; mi < 4; ++mi)
#pragma unroll
    for (int ni = 0; ni < 4; ++ni) acc[mi][ni] = zz;

  for (int k0 = 0; k0 < IN; k0 += 64) {
#pragma unroll
    for (int it = 0; it < 4; ++it) {
      GLOAD_LDS16(aSrc[it] + k0, &As[it * 2048 + tid * 8]);
      GLOAD_LDS16(bSrc[it] + k0, &Bs[it * 2048 + tid * 8]);
    }
    __syncthreads();
#pragma unroll
    for (int kk = 0; kk < 2; ++kk) {
      bf16x8 af[4], bf[4];
#pragma unroll
      for (int mi = 0; mi < 4; ++mi)
        af[mi] = read_frag(As, wm + mi * 16 + (lane & 15), kk, lane);
#pragma unroll
      for (int ni = 0; ni < 4; ++ni)
        bf[ni] = read_frag(Bs, wn + ni * 16 + (lane & 15), kk, lane);
#pragma unroll
      for (int mi = 0; mi < 4; ++mi)
#pragma unroll
        for (int ni = 0; ni < 4; ++ni)
          acc[mi][ni] = __builtin_amdgcn_mfma_f32_16x16x32_bf16(af[mi], bf[ni], acc[mi][ni], 0, 0, 0);
    }
    __syncthreads();
  }

  int rb = mt * 128 + wm + ((lane >> 4) << 2);
  int cbase = nt * 128 + wn + (lane & 15);
#pragma unroll
  for (int mi = 0; mi < 4; ++mi)
#pragma unroll
    for (int r = 0; r < 4; ++r) {
      int mrow = rb + mi * 16 + r;
      if (mrow < cnt) {
        int slot = off + mrow;
        float w = slot_w[slot];
#pragma unroll
        for (int ni = 0; ni < 4; ++ni)
          eo[(size_t)slot * H + cbase + ni * 16] = f2bf(w * acc[mi][ni][r]);
      }
    }
}

// gather: out[n] = eo[slot0] + eo[slot1]
__global__ __launch_bounds__(256) void gather_kernel(
    const ushort* __restrict__ eo, const int* __restrict__ tok2slot,
    float* __restrict__ outF) {
  int idx = blockIdx.x * 256 + threadIdx.x;
  int token = idx >> 8;
  int j = idx & 255;
  int s0 = tok2slot[token * 2 + 0];
  int s1 = tok2slot[token * 2 + 1];
  uint4 a = *(const uint4*)(eo + (size_t)s0 * H + j * 8);
  uint4 b = *(const uint4*)(eo + (size_t)s1 * H + j * 8);
  float4 o0, o1;
  o0.x = bf2f((ushort)(a.x & 0xffff)) + bf2f((ushort)(b.x & 0xffff));
  o0.y = bf2f((ushort)(a.x >> 16))    + bf2f((ushort)(b.x >> 16));
  o0.z = bf2f((ushort)(a.y & 0xffff)) + bf2f((ushort)(b.y & 0xffff));
  o0.w = bf2f((ushort)(a.y >> 16))    + bf2f((ushort)(b.y >> 16));
  o1.x = bf2f((ushort)(a.z & 0xffff)) + bf2f((ushort)(b.z & 0xffff));
  o1.y = bf2f((ushort)(a.z >> 16))    + bf2f((ushort)(b.z >> 16));
  o1.z = bf2f((ushort)(a.w & 0xffff)) + bf2f((ushort)(b.w & 0xffff));
  o1.w = bf2f((ushort)(a.w >> 16))    + bf2f((ushort)(b.w >> 16));
  float4* op = (float4*)(outF + (size_t)token * H + j * 8);
  op[0] = o0; op[1] = o1;
}

extern "C" void kernel_launch(void* const* d_in, const int* in_sizes, int n_in,
                              void* d_out, int out_size, void* d_ws, size_t ws_size,
                              hipStream_t stream) {
  const float* x    = (const float*)d_in[0];
  const float* gw   = (const float*)d_in[1];
  const float* gup  = (const float*)d_in[2];
  const float* down = (const float*)d_in[3];
  float* outF   = (float*)d_out;
  float* logits = outF + (size_t)NTOK * H;

  char* ws = (char*)d_ws;
  size_t o = 0;
  auto alloc = [&](size_t bytes) { char* p = ws + o; o = (o + bytes + 255) & ~(size_t)255; return p; };
  int*    counts     = (int*)alloc(32);
  int*    offsets    = (int*)alloc(32);
  int*    topk_idx   = (int*)alloc((size_t)NTOK * 2 * 4);
  float*  topk_w     = (float*)alloc((size_t)NTOK * 2 * 4);
  int*    slot_token = (int*)alloc((size_t)NSLOT * 4);
  float*  slot_w     = (float*)alloc((size_t)NSLOT * 4);
  int*    tok2slot   = (int*)alloc((size_t)NTOK * 2 * 4);
  ushort* xb         = (ushort*)alloc((size_t)NTOK * H * 2);
  ushort* act        = (ushort*)alloc((size_t)NSLOT * IN * 2);
  ushort* eo         = (ushort*)alloc((size_t)NSLOT * H * 2);
  ushort* gupb       = (ushort*)alloc((size_t)NE * GUPR * H * 2);
  ushort* downb      = (ushort*)alloc((size_t)NE * H * IN * 2);
  if (o > ws_size) return;

  int u1 = NE * GUPR * H / 16;   // 32B-dest units
  int u2 = NE * H * IN / 16;
  prep_kernel<<<NCVT + NTOK, 256, 0, stream>>>(
      x, gw, logits, topk_idx, topk_w, xb,
      (const f32x4*)gup,  (u32x4*)gupb,  u1,
      (const f32x4*)down, (u32x4*)downb, u2);
  scatter_kernel<<<1, 1024, 0, stream>>>(topk_idx, topk_w, counts, offsets,
                                         slot_token, slot_w, tok2slot);
  gemm1_kernel<<<dim3(GUPR / 128, NSLOT / 128, NE), 256, 0, stream>>>(
      xb, gupb, offsets, counts, slot_token, act);
  gemm2_kernel<<<dim3(H / 128, NSLOT / 128, NE), 256, 0, stream>>>(
      act, downb, offsets, counts, slot_w, eo);
  gather_kernel<<<NTOK * H / 8 / 256, 256, 0, stream>>>(eo, tok2slot, outF);
}

// Round 22
// 242.176 us; speedup vs baseline: 1.1112x; 1.1112x over previous
//
#include <hip/hip_runtime.h>
#include <hip/hip_bf16.h>

#define H      2048
#define IN     1408
#define NE     8
#define NTOK   2048
#define NSLOT  (NTOK*2)
#define GUPR   (2*IN)

typedef __attribute__((ext_vector_type(8))) short bf16x8;
typedef __attribute__((ext_vector_type(4))) float f32x4;
typedef __attribute__((ext_vector_type(4))) unsigned int u32x4;

__device__ __forceinline__ ushort f2bf(float f) {
  unsigned u = __float_as_uint(f);
  return (ushort)((u + 0x7FFFu + ((u >> 16) & 1u)) >> 16);
}
__device__ __forceinline__ unsigned pack2(float lo, float hi) {
  return (unsigned)f2bf(lo) | ((unsigned)f2bf(hi) << 16);
}
__device__ __forceinline__ float bf2f(ushort u) {
  return __uint_as_float((unsigned)u << 16);
}

#define GLOAD_LDS16(gp, lp) __builtin_amdgcn_global_load_lds((const __attribute__((address_space(1))) void*)(gp), (__attribute__((address_space(3))) void*)(lp), 16, 0, 0)

// fused prep: blocks [0,NTOK) = router (logits, top-2, xb); blocks [NTOK,..) =
// f32->bf16 weight convert (gate_up row-interleaved, down flat).
// cvt: 32B nontemporal read / 16B write per thread (measured-best variant).
__global__ __launch_bounds__(256) void prep_kernel(
    const float* __restrict__ x, const float* __restrict__ gw,
    float* __restrict__ logits_out,
    int* __restrict__ topk_idx, float* __restrict__ topk_w,
    ushort* __restrict__ xb,
    const f32x4* __restrict__ s1, u32x4* __restrict__ d1, int n1,
    const f32x4* __restrict__ s2, u32x4* __restrict__ d2, int n2) {
  __shared__ float xs[H];
  __shared__ float lg[NE];
  if (blockIdx.x >= NTOK) {
    // ---- cvt path ----
    int i = (blockIdx.x - NTOK) * 256 + threadIdx.x;
    f32x4 a, b;
    u32x4* dp;
    if (i < n1) {
      a = __builtin_nontemporal_load(s1 + 2 * (size_t)i);
      b = __builtin_nontemporal_load(s1 + 2 * (size_t)i + 1);
      int r = i >> 8, c = i & 255;
      int re = r % GUPR;
      int pr = (re < IN) ? (re << 1) : (((re - IN) << 1) | 1);
      dp = d1 + ((size_t)(r - re + pr) * 256 + c);
    } else if (i < n1 + n2) {
      int j = i - n1;
      a = __builtin_nontemporal_load(s2 + 2 * (size_t)j);
      b = __builtin_nontemporal_load(s2 + 2 * (size_t)j + 1);
      dp = d2 + j;
    } else {
      return;
    }
    u32x4 o;
    o.x = pack2(a.x, a.y); o.y = pack2(a.z, a.w);
    o.z = pack2(b.x, b.y); o.w = pack2(b.z, b.w);
    *dp = o;
    return;
  }
  // ---- router path ----
  int n = blockIdx.x;
  const float* xr = x + (size_t)n * H;
  for (int i = threadIdx.x; i < H / 4; i += 256)
    ((float4*)xs)[i] = ((const float4*)xr)[i];
  __syncthreads();
  {
    int t = threadIdx.x;
    float4 v0 = ((const float4*)xs)[t * 2];
    float4 v1 = ((const float4*)xs)[t * 2 + 1];
    uint4 o;
    o.x = pack2(v0.x, v0.y); o.y = pack2(v0.z, v0.w);
    o.z = pack2(v1.x, v1.y); o.w = pack2(v1.z, v1.w);
    *(uint4*)(xb + (size_t)n * H + t * 8) = o;
  }
  int e = threadIdx.x >> 5;
  int l32 = threadIdx.x & 31;
  const float* w = gw + (size_t)e * H;
  float p = 0.f;
  for (int i = l32; i < H; i += 32) p += xs[i] * w[i];
#pragma unroll
  for (int o = 16; o; o >>= 1) p += __shfl_xor(p, o);
  if (l32 == 0) lg[e] = p;
  __syncthreads();
  if (threadIdx.x < NE) logits_out[(size_t)n * NE + threadIdx.x] = lg[threadIdx.x];
  if (threadIdx.x == 0) {
    int i1 = 0; float v1 = lg[0];
    for (int k = 1; k < NE; ++k) if (lg[k] > v1) { v1 = lg[k]; i1 = k; }
    int i2 = -1; float v2 = -1e30f;
    for (int k = 0; k < NE; ++k) if (k != i1 && lg[k] > v2) { v2 = lg[k]; i2 = k; }
    float ed = __expf(v2 - v1);
    topk_idx[n * 2 + 0] = i1; topk_idx[n * 2 + 1] = i2;
    topk_w[n * 2 + 0] = 1.f / (1.f + ed);
    topk_w[n * 2 + 1] = ed / (1.f + ed);
  }
}

// fused count + scan + scatter: ONE block, 1024 threads, LDS counters/cursors
__global__ __launch_bounds__(1024) void scatter_kernel(
    const int* __restrict__ topk_idx, const float* __restrict__ topk_w,
    int* __restrict__ counts, int* __restrict__ offsets,
    int* __restrict__ slot_token, float* __restrict__ slot_w,
    int* __restrict__ tok2slot) {
  __shared__ int cnt_s[NE];
  __shared__ int curs[NE];
  if (threadIdx.x < NE) cnt_s[threadIdx.x] = 0;
  __syncthreads();
  for (int n = threadIdx.x; n < NTOK; n += 1024) {
    atomicAdd(&cnt_s[topk_idx[n * 2 + 0]], 1);
    atomicAdd(&cnt_s[topk_idx[n * 2 + 1]], 1);
  }
  __syncthreads();
  if (threadIdx.x == 0) {
    int s = 0;
    for (int e = 0; e < NE; ++e) {
      counts[e] = cnt_s[e];
      offsets[e] = s; curs[e] = s; s += cnt_s[e];
    }
  }
  __syncthreads();
  for (int n = threadIdx.x; n < NTOK; n += 1024) {
    for (int k = 0; k < 2; ++k) {
      int e = topk_idx[n * 2 + k];
      int s = atomicAdd(&curs[e], 1);
      slot_token[s] = n;
      slot_w[s] = topk_w[n * 2 + k];
      tok2slot[n * 2 + k] = s;
    }
  }
}

// LDS tile [128 rows][64 bf16]; physical 16B-slot q holds logical slot q^(row&7)
__device__ __forceinline__ bf16x8 read_frag(const ushort* lds, int row, int kk, int lane) {
  int slot = (kk * 4 + (lane >> 4)) ^ (row & 7);
  return *(const bf16x8*)(lds + row * 64 + slot * 8);
}

// GEMM1: act = silu(x@Wg^T) * (x@Wu^T)  [R10-proven structure]
// block: 128 slots x 128 interleaved gup rows; BK=64; SINGLE buffer (32KB LDS)
// 4 waves 2Mx2N, wave tile 64x64; silu pairing via shfl_xor(1)
__global__ __launch_bounds__(256) void gemm1_kernel(
    const ushort* __restrict__ xb, const ushort* __restrict__ gupb,
    const int* __restrict__ offsets, const int* __restrict__ counts,
    const int* __restrict__ slot_token, ushort* __restrict__ act) {
  int e = blockIdx.z, mt = blockIdx.y, nt = blockIdx.x;
  int cnt = counts[e];
  if (mt * 128 >= cnt) return;
  int off = offsets[e];
  __shared__ ushort As[128 * 64], Bs[128 * 64];
  int tid = threadIdx.x, lane = tid & 63, wid = tid >> 6;
  int wm = (wid >> 1) * 64, wn = (wid & 1) * 64;
  int q = tid & 7;

  const ushort* aSrc[4];
#pragma unroll
  for (int it = 0; it < 4; ++it) {
    int row = (it * 256 + tid) >> 3;
    int grow = mt * 128 + row; if (grow >= cnt) grow = cnt - 1;
    int token = slot_token[off + grow];
    aSrc[it] = xb + (size_t)token * H + (size_t)((q ^ (row & 7)) * 8);
  }
  const ushort* bSrc[4];
#pragma unroll
  for (int it = 0; it < 4; ++it) {
    int row = (it * 256 + tid) >> 3;
    bSrc[it] = gupb + ((size_t)e * GUPR + nt * 128 + row) * H + (size_t)((q ^ (row & 7)) * 8);
  }

  f32x4 zz = {0.f, 0.f, 0.f, 0.f};
  f32x4 acc[4][4];
#pragma unroll
  for (int mi = 0; mi < 4; ++mi)
#pragma unroll
    for (int ni = 0; ni < 4; ++ni) acc[mi][ni] = zz;

  for (int k0 = 0; k0 < H; k0 += 64) {
#pragma unroll
    for (int it = 0; it < 4; ++it) {
      GLOAD_LDS16(aSrc[it] + k0, &As[it * 2048 + tid * 8]);
      GLOAD_LDS16(bSrc[it] + k0, &Bs[it * 2048 + tid * 8]);
    }
    __syncthreads();
#pragma unroll
    for (int kk = 0; kk < 2; ++kk) {
      bf16x8 af[4], bf[4];
#pragma unroll
      for (int mi = 0; mi < 4; ++mi)
        af[mi] = read_frag(As, wm + mi * 16 + (lane & 15), kk, lane);
#pragma unroll
      for (int ni = 0; ni < 4; ++ni)
        bf[ni] = read_frag(Bs, wn + ni * 16 + (lane & 15), kk, lane);
#pragma unroll
      for (int mi = 0; mi < 4; ++mi)
#pragma unroll
        for (int ni = 0; ni < 4; ++ni)
          acc[mi][ni] = __builtin_amdgcn_mfma_f32_16x16x32_bf16(af[mi], bf[ni], acc[mi][ni], 0, 0, 0);
    }
    __syncthreads();
  }

  // epilogue: permuted col p = wn + ni*16 + (lane&15); even p = gate, odd = up
  int rb = mt * 128 + wm + ((lane >> 4) << 2);
  int colh = (lane & 15) >> 1;
  bool evenlane = (lane & 1) == 0;
#pragma unroll
  for (int mi = 0; mi < 4; ++mi)
#pragma unroll
    for (int r = 0; r < 4; ++r) {
      int mrow = rb + mi * 16 + r;
      bool wr = evenlane && (mrow < cnt);
      size_t rowo = wr ? (size_t)(off + mrow) * IN : 0;
#pragma unroll
      for (int ni = 0; ni < 4; ++ni) {
        float v = acc[mi][ni][r];
        float o = __shfl_xor(v, 1);
        if (wr) {
          float g = v, u = o;
          float a2 = g / (1.f + __expf(-g)) * u;
          act[rowo + nt * 64 + (wn >> 1) + ni * 8 + colh] = f2bf(a2);
        }
      }
    }
}

// GEMM2: eo[slot] = w * (act @ Wd^T)  [R10-proven structure]
// block: 128 slots x 128 H-cols; BK=64; SINGLE buffer; 4 waves 2Mx2N
__global__ __launch_bounds__(256) void gemm2_kernel(
    const ushort* __restrict__ act, const ushort* __restrict__ downb,
    const int* __restrict__ offsets, const int* __restrict__ counts,
    const float* __restrict__ slot_w, ushort* __restrict__ eo) {
  int e = blockIdx.z, mt = blockIdx.y, nt = blockIdx.x;
  int cnt = counts[e];
  if (mt * 128 >= cnt) return;
  int off = offsets[e];
  __shared__ ushort As[128 * 64], Bs[128 * 64];
  int tid = threadIdx.x, lane = tid & 63, wid = tid >> 6;
  int wm = (wid >> 1) * 64, wn = (wid & 1) * 64;
  int q = tid & 7;

  const ushort* aSrc[4];
#pragma unroll
  for (int it = 0; it < 4; ++it) {
    int row = (it * 256 + tid) >> 3;
    int grow = mt * 128 + row; if (grow >= cnt) grow = cnt - 1;
    aSrc[it] = act + (size_t)(off + grow) * IN + (size_t)((q ^ (row & 7)) * 8);
  }
  const ushort* bSrc[4];
#pragma unroll
  for (int it = 0; it < 4; ++it) {
    int row = (it * 256 + tid) >> 3;
    bSrc[it] = downb + ((size_t)e * H + nt * 128 + row) * IN + (size_t)((q ^ (row & 7)) * 8);
  }

  f32x4 zz = {0.f, 0.f, 0.f, 0.f};
  f32x4 acc[4][4];
#pragma unroll
  for (int mi = 0; mi < 4; ++mi)
#pragma unroll
    for (int ni = 0; ni < 4; ++ni) acc[mi][ni] = zz;

  for (int k0 = 0; k0 < IN; k0 += 64) {
#pragma unroll
    for (int it = 0; it < 4; ++it) {
      GLOAD_LDS16(aSrc[it] + k0, &As[it * 2048 + tid * 8]);
      GLOAD_LDS16(bSrc[it] + k0, &Bs[it * 2048 + tid * 8]);
    }
    __syncthreads();
#pragma unroll
    for (int kk = 0; kk < 2; ++kk) {
      bf16x8 af[4], bf[4];
#pragma unroll
      for (int mi = 0; mi < 4; ++mi)
        af[mi] = read_frag(As, wm + mi * 16 + (lane & 15), kk, lane);
#pragma unroll
      for (int ni = 0; ni < 4; ++ni)
        bf[ni] = read_frag(Bs, wn + ni * 16 + (lane & 15), kk, lane);
#pragma unroll
      for (int mi = 0; mi < 4; ++mi)
#pragma unroll
        for (int ni = 0; ni < 4; ++ni)
          acc[mi][ni] = __builtin_amdgcn_mfma_f32_16x16x32_bf16(af[mi], bf[ni], acc[mi][ni], 0, 0, 0);
    }
    __syncthreads();
  }

  int rb = mt * 128 + wm + ((lane >> 4) << 2);
  int cbase = nt * 128 + wn + (lane & 15);
#pragma unroll
  for (int mi = 0; mi < 4; ++mi)
#pragma unroll
    for (int r = 0; r < 4; ++r) {
      int mrow = rb + mi * 16 + r;
      if (mrow < cnt) {
        int slot = off + mrow;
        float w = slot_w[slot];
#pragma unroll
        for (int ni = 0; ni < 4; ++ni)
          eo[(size_t)slot * H + cbase + ni * 16] = f2bf(w * acc[mi][ni][r]);
      }
    }
}

// gather: out[n] = eo[slot0] + eo[slot1]
__global__ __launch_bounds__(256) void gather_kernel(
    const ushort* __restrict__ eo, const int* __restrict__ tok2slot,
    float* __restrict__ outF) {
  int idx = blockIdx.x * 256 + threadIdx.x;
  int token = idx >> 8;
  int j = idx & 255;
  int s0 = tok2slot[token * 2 + 0];
  int s1 = tok2slot[token * 2 + 1];
  uint4 a = *(const uint4*)(eo + (size_t)s0 * H + j * 8);
  uint4 b = *(const uint4*)(eo + (size_t)s1 * H + j * 8);
  float4 o0, o1;
  o0.x = bf2f((ushort)(a.x & 0xffff)) + bf2f((ushort)(b.x & 0xffff));
  o0.y = bf2f((ushort)(a.x >> 16))    + bf2f((ushort)(b.x >> 16));
  o0.z = bf2f((ushort)(a.y & 0xffff)) + bf2f((ushort)(b.y & 0xffff));
  o0.w = bf2f((ushort)(a.y >> 16))    + bf2f((ushort)(b.y >> 16));
  o1.x = bf2f((ushort)(a.z & 0xffff)) + bf2f((ushort)(b.z & 0xffff));
  o1.y = bf2f((ushort)(a.z >> 16))    + bf2f((ushort)(b.z >> 16));
  o1.z = bf2f((ushort)(a.w & 0xffff)) + bf2f((ushort)(b.w & 0xffff));
  o1.w = bf2f((ushort)(a.w >> 16))    + bf2f((ushort)(b.w >> 16));
  float4* op = (float4*)(outF + (size_t)token * H + j * 8);
  op[0] = o0; op[1] = o1;
}

extern "C" void kernel_launch(void* const* d_in, const int* in_sizes, int n_in,
                              void* d_out, int out_size, void* d_ws, size_t ws_size,
                              hipStream_t stream) {
  const float* x    = (const float*)d_in[0];
  const float* gw   = (const float*)d_in[1];
  const float* gup  = (const float*)d_in[2];
  const float* down = (const float*)d_in[3];
  float* outF   = (float*)d_out;
  float* logits = outF + (size_t)NTOK * H;

  char* ws = (char*)d_ws;
  size_t o = 0;
  auto alloc = [&](size_t bytes) { char* p = ws + o; o = (o + bytes + 255) & ~(size_t)255; return p; };
  int*    counts     = (int*)alloc(32);
  int*    offsets    = (int*)alloc(32);
  int*    topk_idx   = (int*)alloc((size_t)NTOK * 2 * 4);
  float*  topk_w     = (float*)alloc((size_t)NTOK * 2 * 4);
  int*    slot_token = (int*)alloc((size_t)NSLOT * 4);
  float*  slot_w     = (float*)alloc((size_t)NSLOT * 4);
  int*    tok2slot   = (int*)alloc((size_t)NTOK * 2 * 4);
  ushort* xb         = (ushort*)alloc((size_t)NTOK * H * 2);
  ushort* act        = (ushort*)alloc((size_t)NSLOT * IN * 2);
  ushort* eo         = (ushort*)alloc((size_t)NSLOT * H * 2);
  ushort* gupb       = (ushort*)alloc((size_t)NE * GUPR * H * 2);
  ushort* downb      = (ushort*)alloc((size_t)NE * H * IN * 2);
  if (o > ws_size) return;

  int n1 = NE * GUPR * H / 8;
  int n2 = NE * H * IN / 8;
  int nblk = (n1 + n2 + 255) / 256;
  prep_kernel<<<NTOK + nblk, 256, 0, stream>>>(
      x, gw, logits, topk_idx, topk_w, xb,
      (const f32x4*)gup,  (u32x4*)gupb,  n1,
      (const f32x4*)down, (u32x4*)downb, n2);
  scatter_kernel<<<1, 1024, 0, stream>>>(topk_idx, topk_w, counts, offsets,
                                         slot_token, slot_w, tok2slot);
  gemm1_kernel<<<dim3(GUPR / 128, NSLOT / 128, NE), 256, 0, stream>>>(
      xb, gupb, offsets, counts, slot_token, act);
  gemm2_kernel<<<dim3(H / 128, NSLOT / 128, NE), 256, 0, stream>>>(
      act, downb, offsets, counts, slot_w, eo);
  gather_kernel<<<NTOK * H / 8 / 256, 256, 0, stream>>>(eo, tok2slot, outF);
}